// Round 13
// baseline (304.205 us; speedup 1.0000x reference)
//
#include <hip/hip_runtime.h>

typedef unsigned short u16;
typedef __attribute__((ext_vector_type(8))) short bf16x8;
typedef __attribute__((ext_vector_type(4))) float f32x4;

#define LOG2E 1.4426950408889634f
#define QSCALE (LOG2E / 8.0f)   // fold 1/sqrt(64) and ln->log2 into Q projection

__device__ __forceinline__ u16 f2bf(float f) {
  union { float f; unsigned u; } v; v.f = f;
  unsigned r = v.u + 0x7fffu + ((v.u >> 16) & 1u);   // RNE
  return (u16)(r >> 16);
}

__device__ __forceinline__ float bf2f(u16 u) {
  union { unsigned u; float f; } v; v.u = (unsigned)u << 16; return v.f;
}

// async global->LDS, 16B per lane. LDS dest must be wave-uniform base + lane*16.
__device__ __forceinline__ void gload_lds16(const void* g, void* l) {
  __builtin_amdgcn_global_load_lds(
      (const __attribute__((address_space(1))) unsigned int*)(unsigned long long)g,
      (__attribute__((address_space(3))) unsigned int*)(unsigned int)(unsigned long long)l,
      16, 0, 0);
}

// ---------------- fused prep: 7x f32->bf16 convert + mask bit-pack ----------------
__global__ __launch_bounds__(256) void prep_kernel(
    const float* __restrict__ q, const float* __restrict__ k, const float* __restrict__ v,
    const float* __restrict__ wq, const float* __restrict__ wk, const float* __restrict__ wv,
    const float* __restrict__ wo, const int* __restrict__ mask,
    u16* __restrict__ Xq, u16* __restrict__ Xk, u16* __restrict__ Xv,
    u16* __restrict__ Wq, u16* __restrict__ Wk, u16* __restrict__ Wv, u16* __restrict__ Wo,
    unsigned long long* __restrict__ Mp) {
  const int bx = blockIdx.x;
  if (bx < 16384) {
    const float* src; u16* dst; float sc; int idx;
    if (bx < 12288) {
      int seg = bx >> 12;
      idx = (bx & 4095) * 256 + threadIdx.x;
      src = seg == 0 ? q : (seg == 1 ? k : v);
      dst = seg == 0 ? Xq : (seg == 1 ? Xk : Xv);
      sc = 1.f;
    } else {
      int t = bx - 12288, seg = t >> 10;
      idx = (t & 1023) * 256 + threadIdx.x;
      src = seg == 0 ? wq : (seg == 1 ? wk : (seg == 2 ? wv : wo));
      dst = seg == 0 ? Wq : (seg == 1 ? Wk : (seg == 2 ? Wv : Wo));
      sc = seg == 0 ? QSCALE : 1.f;
    }
    float4 x = ((const float4*)src)[idx];
    ushort4 o;
    o.x = f2bf(x.x * sc); o.y = f2bf(x.y * sc);
    o.z = f2bf(x.z * sc); o.w = f2bf(x.w * sc);
    ((ushort4*)dst)[idx] = o;
  } else {
    int gw = (((bx - 16384) * 256) + threadIdx.x) >> 6;   // [0,16384)
    int lane = threadIdx.x & 63;
    for (int w = gw; w < 131072; w += 16384) {
      int m = mask[(size_t)w * 64 + lane];
      unsigned long long b = __ballot(m != 0);
      if (lane == 0) Mp[w] = b;
    }
  }
}

// ---------------- fused GEMM: D[m][n] = sum_k A[m][k]*B[n][k]  (both k-contig, lda=ldb=1024)
// mode 0: A=Wq(f) B=Xq(s) -> Qd[b,h,s,d] bf16 (+bq*QSCALE)
// mode 1: A=Wk    B=Xk    -> Kd[b,h,s,d] bf16 (+bk)
// mode 2: A=Xv(s) B=Wv(f) -> Vtd[b,h,d,s] bf16 (+bv)
// mode 3/4: A=Wo(f) B=ctx(s) K-half z=mode-3 -> bf16 partial outp[z][s][f]
//   (R12: K-split z=2 -> 512 blocks = 2 blocks/CU. Partials summed in LN (f32).)
// R17: BK 32->64. As/Bs = 16KB each ([kc 8][row 128][8]) -> 32KB, still under the 34KB SH
// the epilogue already forces (m132's BK=128 occupancy cliff doesn't apply). K-steps and
// barrier count halve (64 -> 32 barriers); MFMA per barrier-pair doubles (16 -> 32).
// Same k-ascending FLOP order -> bit-identical results.
__global__ __launch_bounds__(256, 3) void gemm_kernel(
    const u16* __restrict__ Xq, const u16* __restrict__ Xk, const u16* __restrict__ Xv,
    const u16* __restrict__ Wq, const u16* __restrict__ Wk, const u16* __restrict__ Wv,
    const u16* __restrict__ Wo, const u16* __restrict__ Ctx,
    const float* __restrict__ bq, const float* __restrict__ bk, const float* __restrict__ bv,
    u16* __restrict__ Qd, u16* __restrict__ Kd, u16* __restrict__ Vtd, u16* __restrict__ outp,
    int mode_base) {
  __shared__ __align__(16) u16 SH[17408];  // main loop: As[8192]+Bs[8192]; epilogue: 34KB transpose tile
  u16* As = SH;
  u16* Bs = SH + 8192;
  const int mode = mode_base + blockIdx.z;
  const int tid = threadIdx.x;
  const int wid = tid >> 6, l = tid & 63, quad = l >> 4, ln = l & 15;
  const int wm = wid >> 1, wn = wid & 1;

  const u16 *A, *B; const float* bias;
  if (mode == 0)      { A = Wq; B = Xq;  bias = bq; }
  else if (mode == 1) { A = Wk; B = Xk;  bias = bk; }
  else if (mode == 2) { A = Xv; B = Wv;  bias = bv; }
  else                { A = Wo; B = Ctx; bias = bq; }
  int mBase, nBase;
  if (mode == 2) { mBase = blockIdx.x * 128; nBase = blockIdx.y * 128; }
  else           { mBase = blockIdx.y * 128; nBase = blockIdx.x * 128; }

  const int koff = (mode >= 3) ? (mode - 3) * 512 : 0;
  const int kLen = (mode >= 3) ? 512 : 1024;
  const u16* Ag = A + (size_t)mBase * 1024 + koff;
  const u16* Bg = B + (size_t)nBase * 1024 + koff;

  f32x4 acc[4][4] = {};

  for (int k0 = 0; k0 < kLen; k0 += 64) {
    if (k0) __syncthreads();
    {
#pragma unroll
      for (int r = 0; r < 4; ++r) {
        int i = r * 256 + tid;  // [0,1024): kc = i>>7 in [0,8), row = i&127
        gload_lds16(Ag + (size_t)(i & 127) * 1024 + k0 + (i >> 7) * 8, &As[i * 8]);
        gload_lds16(Bg + (size_t)(i & 127) * 1024 + k0 + (i >> 7) * 8, &Bs[i * 8]);
      }
    }
    __syncthreads();
#pragma unroll
    for (int kk = 0; kk < 2; ++kk) {
      bf16x8 af[4], bf[4];
#pragma unroll
      for (int i = 0; i < 4; ++i)
        af[i] = *(const bf16x8*)&As[((kk * 4 + quad) * 128 + wm * 64 + i * 16 + ln) * 8];
#pragma unroll
      for (int j = 0; j < 4; ++j)
        bf[j] = *(const bf16x8*)&Bs[((kk * 4 + quad) * 128 + wn * 64 + j * 16 + ln) * 8];
#pragma unroll
      for (int i = 0; i < 4; ++i)
#pragma unroll
        for (int j = 0; j < 4; ++j)
          acc[i][j] = __builtin_amdgcn_mfma_f32_16x16x32_bf16(af[i], bf[j], acc[i][j], 0, 0, 0);
    }
  }

  __syncthreads();  // all waves done with As/Bs before reusing SH for the transpose

  if (mode <= 1) {
    const float bscale = (mode == 0) ? QSCALE : 1.0f;
#pragma unroll
    for (int i = 0; i < 4; ++i) {
      int f0 = wm * 64 + i * 16 + quad * 4;
      float4 bb = *(const float4*)(bias + mBase + f0);
#pragma unroll
      for (int j = 0; j < 4; ++j) {
        int sl = wn * 64 + j * 16 + ln;
        f32x4 v = acc[i][j];
        ushort4 o;
        o.x = f2bf(v[0] + bb.x * bscale); o.y = f2bf(v[1] + bb.y * bscale);
        o.z = f2bf(v[2] + bb.z * bscale); o.w = f2bf(v[3] + bb.w * bscale);
        *(ushort4*)&SH[sl * 136 + f0] = o;
      }
    }
    __syncthreads();
    u16* dstQK = (mode == 0) ? Qd : Kd;
#pragma unroll
    for (int p = 0; p < 8; ++p) {
      int sl = p * 16 + (tid >> 4);
      int fl = (tid & 15) * 8;
      uint4 w = *(const uint4*)&SH[sl * 136 + fl];
      int s = nBase + sl, f = mBase + fl;
      int h = f >> 6, d = f & 63, b = s >> 11, sr = s & 2047;
      *(uint4*)(dstQK + (((size_t)(b * 16 + h) * 2048 + sr) * 64 + d)) = w;
    }
  } else if (mode == 2) {
#pragma unroll
    for (int j = 0; j < 4; ++j) {
      int fl = wn * 64 + j * 16 + ln;
      float bb = bias[nBase + fl];
#pragma unroll
      for (int i = 0; i < 4; ++i) {
        int s0 = wm * 64 + i * 16 + quad * 4;
        f32x4 v = acc[i][j];
        ushort4 o;
        o.x = f2bf(v[0] + bb); o.y = f2bf(v[1] + bb);
        o.z = f2bf(v[2] + bb); o.w = f2bf(v[3] + bb);
        *(ushort4*)&SH[fl * 136 + s0] = o;
      }
    }
    __syncthreads();
#pragma unroll
    for (int p = 0; p < 8; ++p) {
      int fl = p * 16 + (tid >> 4);
      int sl = (tid & 15) * 8;
      uint4 w = *(const uint4*)&SH[fl * 136 + sl];
      int f = nBase + fl, s = mBase + sl;
      int h = f >> 6, d = f & 63, b = s >> 11, sr = s & 2047;
      *(uint4*)(Vtd + (((size_t)(b * 16 + h) * 64 + d) * 2048 + sr)) = w;
    }
  } else {
    // modes 3/4: bf16 partial, same SH-transpose as mode<=1, no bias, linear [s][f] dst
    u16* dst = outp + (size_t)(mode - 3) * (4096u * 1024u);
#pragma unroll
    for (int i = 0; i < 4; ++i) {
      int f0 = wm * 64 + i * 16 + quad * 4;
#pragma unroll
      for (int j = 0; j < 4; ++j) {
        int sl = wn * 64 + j * 16 + ln;
        f32x4 v = acc[i][j];
        ushort4 o;
        o.x = f2bf(v[0]); o.y = f2bf(v[1]);
        o.z = f2bf(v[2]); o.w = f2bf(v[3]);
        *(ushort4*)&SH[sl * 136 + f0] = o;
      }
    }
    __syncthreads();
#pragma unroll
    for (int p = 0; p < 8; ++p) {
      int sl = p * 16 + (tid >> 4);
      int fl = (tid & 15) * 8;
      uint4 w = *(const uint4*)&SH[sl * 136 + fl];
      *(uint4*)(dst + (size_t)(nBase + sl) * 1024 + mBase + fl) = w;
    }
  }
}

// ---------------- flash attention (no-max exp2 softmax), 128-q tiles, XCD-swizzled ----------------
// R16 (frozen): 512 blocks x 512 threads (8 waves, 16-q band each), QBLK=128 KVBLK=128,
// 2-phase dbuf staging via global_load_lds (R7), trunc-pack + setprio (R9), P stride-64
// XOR-swizzle. 2x80KiB LDS = 160KiB/CU, 16 waves/CU. >=2 blocks/CU is a hard constraint
// (R10/R12/R15: the per-tile vmcnt(0) drain needs a co-resident block to hide under).
__global__ __launch_bounds__(512, 4) void attn_kernel(
    const u16* __restrict__ Qg, const u16* __restrict__ Kg, const u16* __restrict__ Vtg,
    const unsigned* __restrict__ Mp, u16* __restrict__ ctx) {
  __shared__ __align__(16) u16 Ks0[8192];  // [dg 8][kv 128][8]
  __shared__ __align__(16) u16 Ks1[8192];
  __shared__ __align__(16) u16 Vs0[8192];  // [kvg 16][d 64][8]
  __shared__ __align__(16) u16 Vs1[8192];
  __shared__ __align__(16) u16 Ps[8192];   // [q 128][64] swizzled; reused as Os[128][64]
  const int tid = threadIdx.x;             // 0..511
  const int wid = tid >> 6, l = tid & 63, quad = l >> 4, ln = l & 15;
  const int q4 = quad * 4;
  const int L = blockIdx.x;
  const int bh = (L & 7) + 8 * (L >> 7);
  const int b = bh >> 4, h = bh & 15;
  const int qBase = ((L >> 3) & 15) * 128;
  const int wq = wid * 16;                 // wave's 16-q band (wid 0..7)
  const int sw = (ln & 7) << 3;            // P row XOR-swizzle, u16 units (row&7 == ln&7)

  bf16x8 qf[2];  // B-operand fragments of Q (col=q=ln row, k=d contiguous)
#pragma unroll
  for (int kc = 0; kc < 2; ++kc)
    qf[kc] = *(const bf16x8*)(Qg + (((size_t)bh * 2048 + qBase + wq + ln) * 64 +
                                    kc * 32 + quad * 8));

  f32x4 oacc[4] = {};
  f32x4 lsum = {};
  const bf16x8 vone = {(short)0x3F80, (short)0x3F80, (short)0x3F80, (short)0x3F80,
                       (short)0x3F80, (short)0x3F80, (short)0x3F80, (short)0x3F80};

  const unsigned* mrow = Mp + ((size_t)b * 2048 + qBase + wq + ln) * 64;  // 64 u32 / row

  const u16* KgB = Kg + (size_t)bh * 2048 * 64;
  const u16* VgB = Vtg + (size_t)bh * 64 * 2048;

#define STAGE_TILE(KS, VS, t_)                                                  \
  do {                                                                          \
    const int kvB_ = (t_) * 128;                                                \
    _Pragma("unroll")                                                           \
    for (int r_ = 0; r_ < 2; ++r_) {                                            \
      int c_ = r_ * 512 + tid;                                                  \
      gload_lds16(KgB + (size_t)(kvB_ + (c_ & 127)) * 64 + (c_ >> 7) * 8,       \
                  &KS[c_ * 8]);                                                 \
      gload_lds16(VgB + (size_t)(c_ & 63) * 2048 + kvB_ + (c_ >> 6) * 8,        \
                  &VS[c_ * 8]);                                                 \
    }                                                                           \
  } while (0)

#define COMPUTE_TILE(KS, VS, it_)                                                         \
  do {                                                                                    \
    unsigned ww[4];                                                                       \
    {                                                                                     \
      uint4 m0 = *(const uint4*)(mrow + (it_) * 4);                                       \
      ww[0] = m0.x; ww[1] = m0.y; ww[2] = m0.z; ww[3] = m0.w;                             \
    }                                                                                     \
    _Pragma("unroll")                                                                     \
    for (int hf = 0; hf < 2; ++hf) {                                                      \
      f32x4 s[4];                                                                         \
      __builtin_amdgcn_s_setprio(1);                                                      \
      _Pragma("unroll")                                                                   \
      for (int m2 = 0; m2 < 4; ++m2) {                                                    \
        int mt = hf * 4 + m2;                                                             \
        bf16x8 k0 = *(const bf16x8*)&KS[((0 + quad) * 128 + mt * 16 + ln) * 8];           \
        bf16x8 k1 = *(const bf16x8*)&KS[((4 + quad) * 128 + mt * 16 + ln) * 8];           \
        f32x4 z = {0.f, 0.f, 0.f, 0.f};                                                   \
        z = __builtin_amdgcn_mfma_f32_16x16x32_bf16(k0, qf[0], z, 0, 0, 0);               \
        s[m2] = __builtin_amdgcn_mfma_f32_16x16x32_bf16(k1, qf[1], z, 0, 0, 0);           \
      }                                                                                   \
      __builtin_amdgcn_s_setprio(0);                                                      \
      uint2 pk[4];                                                                        \
      _Pragma("unroll")                                                                   \
      for (int m2 = 0; m2 < 4; ++m2) {                                                    \
        int mt = hf * 4 + m2;                                                             \
        unsigned nib = (ww[mt >> 1] >> ((mt & 1) * 16 + q4)) & 0xFu;                      \
        float p0 = __builtin_amdgcn_exp2f((nib & 1u) ? s[m2][0] : -1e30f);                \
        float p1 = __builtin_amdgcn_exp2f((nib & 2u) ? s[m2][1] : -1e30f);                \
        float p2 = __builtin_amdgcn_exp2f((nib & 4u) ? s[m2][2] : -1e30f);                \
        float p3 = __builtin_amdgcn_exp2f((nib & 8u) ? s[m2][3] : -1e30f);                \
        pk[m2].x = __builtin_amdgcn_perm(__float_as_uint(p1), __float_as_uint(p0),        \
                                         0x07060302u);                                    \
        pk[m2].y = __builtin_amdgcn_perm(__float_as_uint(p3), __float_as_uint(p2),        \
                                         0x07060302u);                                    \
      }                                                                                   \
      /* P write -> PV read is intra-wave (own 16-row band): no barrier needed. */        \
      _Pragma("unroll")                                                                   \
      for (int m2 = 0; m2 < 4; ++m2)                                                      \
        *(uint2*)&Ps[(((wq + ln) * 64) + m2 * 16 + q4) ^ sw] = pk[m2];                    \
      __builtin_amdgcn_s_setprio(1);                                                      \
      _Pragma("unroll")                                                                   \
      for (int k2 = 0; k2 < 2; ++k2) {                                                    \
        int kc2 = hf * 2 + k2;                                                            \
        bf16x8 aP = *(const bf16x8*)&Ps[(((wq + ln) * 64) + k2 * 32 + quad * 8) ^ sw];    \
        _Pragma("unroll")                                                                 \
        for (int nt = 0; nt < 4; ++nt) {                                                  \
          bf16x8 bV = *(const bf16x8*)&VS[((kc2 * 4 + quad) * 64 + nt * 16 + ln) * 8];    \
          oacc[nt] = __builtin_amdgcn_mfma_f32_16x16x32_bf16(aP, bV, oacc[nt], 0, 0, 0);  \
        }                                                                                 \
        lsum = __builtin_amdgcn_mfma_f32_16x16x32_bf16(aP, vone, lsum, 0, 0, 0);          \
      }                                                                                   \
      __builtin_amdgcn_s_setprio(0);                                                      \
    }                                                                                     \
  } while (0)

  STAGE_TILE(Ks0, Vs0, 0);  // prologue: tile 0 -> buf0 (drain cost paid once)
#pragma unroll 1
  for (int it2 = 0; it2 < 8; ++it2) {
    __syncthreads();  // drains buf0 staging (issued one compute-phase ago); buf1 readers done
    STAGE_TILE(Ks1, Vs1, 2 * it2 + 1);
    COMPUTE_TILE(Ks0, Vs0, 2 * it2);
    __syncthreads();  // drains buf1 staging; buf0 readers done
    if (it2 < 7) STAGE_TILE(Ks0, Vs0, 2 * it2 + 2);
    COMPUTE_TILE(Ks1, Vs1, 2 * it2 + 1);
  }
#undef STAGE_TILE
#undef COMPUTE_TILE

  // epilogue: stage normalized O into Ps (own band only; P and Os bands coincide at stride 64)
  __syncthreads();  // all waves done with Ps as P
#pragma unroll
  for (int r = 0; r < 4; ++r) {
    float il = 1.0f / lsum[r];
    int q = wq + q4 + r;
#pragma unroll
    for (int nt = 0; nt < 4; ++nt)
      Ps[q * 64 + nt * 16 + ln] = f2bf(oacc[nt][r] * il);
  }
  __syncthreads();
#pragma unroll
  for (int r = 0; r < 2; ++r) {
    int c = r * 512 + tid;
    int q = c >> 3, ch = c & 7;
    *(uint4*)(ctx + ((size_t)(b * 2048 + qBase + q) * 1024 + h * 64 + ch * 8)) =
        *(const uint4*)&Ps[q * 64 + ch * 8];
  }
}

// ---------------- LayerNorm (fused partial-sum + bo + residual) over 1024 features ----------------
// R12: x is TWO bf16 K-half partials (8MB each); sum in f32 here.
__global__ __launch_bounds__(256) void ln_kernel(const u16* __restrict__ xp,
                                                 const float* __restrict__ resid,
                                                 const float* __restrict__ bo,
                                                 const float* __restrict__ gamma,
                                                 const float* __restrict__ beta,
                                                 float* __restrict__ out) {
  __shared__ float red[8];
  const int tid = threadIdx.x;
  const size_t row = blockIdx.x;
  ushort4 pa = ((const ushort4*)(xp + row * 1024))[tid];
  ushort4 pb = ((const ushort4*)(xp + 4096u * 1024u + row * 1024))[tid];
  const float4 rr = ((const float4*)(resid + row * 1024))[tid];
  const float4 bb = ((const float4*)bo)[tid];
  float4 v;
  v.x = bf2f(pa.x) + bf2f(pb.x) + rr.x + bb.x;
  v.y = bf2f(pa.y) + bf2f(pb.y) + rr.y + bb.y;
  v.z = bf2f(pa.z) + bf2f(pb.z) + rr.z + bb.z;
  v.w = bf2f(pa.w) + bf2f(pb.w) + rr.w + bb.w;
  float s1 = v.x + v.y + v.z + v.w;
  float s2 = v.x * v.x + v.y * v.y + v.z * v.z + v.w * v.w;
#pragma unroll
  for (int o = 32; o >= 1; o >>= 1) {
    s1 += __shfl_xor(s1, o);
    s2 += __shfl_xor(s2, o);
  }
  if ((tid & 63) == 0) { red[(tid >> 6) * 2] = s1; red[(tid >> 6) * 2 + 1] = s2; }
  __syncthreads();
  s1 = red[0] + red[2] + red[4] + red[6];
  s2 = red[1] + red[3] + red[5] + red[7];
  float mu = s1 * (1.f / 1024.f);
  float var = s2 * (1.f / 1024.f) - mu * mu;
  float inv = rsqrtf(var + 1e-5f);
  float4 g = ((const float4*)gamma)[tid];
  float4 be = ((const float4*)beta)[tid];
  float4 o;
  o.x = (v.x - mu) * inv * g.x + be.x;
  o.y = (v.y - mu) * inv * g.y + be.y;
  o.z = (v.z - mu) * inv * g.z + be.z;
  o.w = (v.w - mu) * inv * g.w + be.w;
  ((float4*)(out + row * 1024))[tid] = o;
}

extern "C" void kernel_launch(void* const* d_in, const int* in_sizes, int n_in,
                              void* d_out, int out_size, void* d_ws, size_t ws_size,
                              hipStream_t stream) {
  const float* query = (const float*)d_in[0];
  const float* key   = (const float*)d_in[1];
  const float* value = (const float*)d_in[2];
  const int*   mask  = (const int*)d_in[3];
  const float* w_q = (const float*)d_in[4];
  const float* b_q = (const float*)d_in[5];
  const float* w_k = (const float*)d_in[6];
  const float* b_k = (const float*)d_in[7];
  const float* w_v = (const float*)d_in[8];
  const float* b_v = (const float*)d_in[9];
  const float* w_o = (const float*)d_in[10];
  const float* b_o = (const float*)d_in[11];
  const float* ln_g = (const float*)d_in[12];
  const float* ln_b = (const float*)d_in[13];
  float* out = (float*)d_out;

  char* ws = (char*)d_ws;
  u16* Xq = (u16*)(ws + ((size_t)0 << 20));   // 8MB, reused as ctx after QKV GEMM
  u16* Xk = (u16*)(ws + ((size_t)8 << 20));   // 8MB  } reused as outpre (2x8MB bf16 partials)
  u16* Xv = (u16*)(ws + ((size_t)16 << 20));  // 8MB  }
  u16* outpre = (u16*)(ws + ((size_t)8 << 20));
  u16* Wq = (u16*)(ws + ((size_t)24 << 20));
  u16* Wk = (u16*)(ws + ((size_t)26 << 20));
  u16* Wv = (u16*)(ws + ((size_t)28 << 20));
  u16* Wo = (u16*)(ws + ((size_t)30 << 20));
  u16* Qd = (u16*)(ws + ((size_t)32 << 20));   // [b,h,s,64] bf16
  u16* Kd = (u16*)(ws + ((size_t)40 << 20));   // [b,h,s,64]
  u16* Vtd = (u16*)(ws + ((size_t)48 << 20));  // [b,h,64,s]
  unsigned long long* Mp = (unsigned long long*)(ws + ((size_t)56 << 20));  // 1MB
  u16* ctx = Xq;

  prep_kernel<<<20480, 256, 0, stream>>>(query, key, value, w_q, w_k, w_v, w_o, mask,
                                         Xq, Xk, Xv, Wq, Wk, Wv, Wo, Mp);
  gemm_kernel<<<dim3(32, 8, 3), 256, 0, stream>>>(Xq, Xk, Xv, Wq, Wk, Wv, Wo, ctx,
      b_q, b_k, b_v, Qd, Kd, Vtd, outpre, 0);
  attn_kernel<<<dim3(512), 512, 0, stream>>>(Qd, Kd, Vtd, (const unsigned*)Mp, ctx);
  gemm_kernel<<<dim3(32, 8, 2), 256, 0, stream>>>(Xq, Xk, Xv, Wq, Wk, Wv, Wo, ctx,
      b_q, b_k, b_v, Qd, Kd, Vtd, outpre, 3);
  ln_kernel<<<4096, 256, 0, stream>>>(outpre, query, b_o, ln_g, ln_b, out);
}

// Round 14
// 295.044 us; speedup vs baseline: 1.0310x; 1.0310x over previous
//
#include <hip/hip_runtime.h>

typedef unsigned short u16;
typedef __attribute__((ext_vector_type(8))) short bf16x8;
typedef __attribute__((ext_vector_type(4))) float f32x4;

#define LOG2E 1.4426950408889634f
#define QSCALE (LOG2E / 8.0f)   // fold 1/sqrt(64) and ln->log2 into Q projection

__device__ __forceinline__ u16 f2bf(float f) {
  union { float f; unsigned u; } v; v.f = f;
  unsigned r = v.u + 0x7fffu + ((v.u >> 16) & 1u);   // RNE
  return (u16)(r >> 16);
}

__device__ __forceinline__ float bf2f(u16 u) {
  union { unsigned u; float f; } v; v.u = (unsigned)u << 16; return v.f;
}

// async global->LDS, 16B per lane. LDS dest must be wave-uniform base + lane*16.
__device__ __forceinline__ void gload_lds16(const void* g, void* l) {
  __builtin_amdgcn_global_load_lds(
      (const __attribute__((address_space(1))) unsigned int*)(unsigned long long)g,
      (__attribute__((address_space(3))) unsigned int*)(unsigned int)(unsigned long long)l,
      16, 0, 0);
}

// ---------------- fused prep: 7x f32->bf16 convert + mask bit-pack ----------------
__global__ __launch_bounds__(256) void prep_kernel(
    const float* __restrict__ q, const float* __restrict__ k, const float* __restrict__ v,
    const float* __restrict__ wq, const float* __restrict__ wk, const float* __restrict__ wv,
    const float* __restrict__ wo, const int* __restrict__ mask,
    u16* __restrict__ Xq, u16* __restrict__ Xk, u16* __restrict__ Xv,
    u16* __restrict__ Wq, u16* __restrict__ Wk, u16* __restrict__ Wv, u16* __restrict__ Wo,
    unsigned long long* __restrict__ Mp) {
  const int bx = blockIdx.x;
  if (bx < 16384) {
    const float* src; u16* dst; float sc; int idx;
    if (bx < 12288) {
      int seg = bx >> 12;
      idx = (bx & 4095) * 256 + threadIdx.x;
      src = seg == 0 ? q : (seg == 1 ? k : v);
      dst = seg == 0 ? Xq : (seg == 1 ? Xk : Xv);
      sc = 1.f;
    } else {
      int t = bx - 12288, seg = t >> 10;
      idx = (t & 1023) * 256 + threadIdx.x;
      src = seg == 0 ? wq : (seg == 1 ? wk : (seg == 2 ? wv : wo));
      dst = seg == 0 ? Wq : (seg == 1 ? Wk : (seg == 2 ? Wv : Wo));
      sc = seg == 0 ? QSCALE : 1.f;
    }
    float4 x = ((const float4*)src)[idx];
    ushort4 o;
    o.x = f2bf(x.x * sc); o.y = f2bf(x.y * sc);
    o.z = f2bf(x.z * sc); o.w = f2bf(x.w * sc);
    ((ushort4*)dst)[idx] = o;
  } else {
    int gw = (((bx - 16384) * 256) + threadIdx.x) >> 6;   // [0,16384)
    int lane = threadIdx.x & 63;
    for (int w = gw; w < 131072; w += 16384) {
      int m = mask[(size_t)w * 64 + lane];
      unsigned long long b = __ballot(m != 0);
      if (lane == 0) Mp[w] = b;
    }
  }
}

// ---------------- fused GEMM: D[m][n] = sum_k A[m][k]*B[n][k]  (both k-contig, lda=ldb=1024)
// mode 0: A=Wq(f) B=Xq(s) -> Qd[b,h,s,d] bf16 (+bq*QSCALE)
// mode 1: A=Wk    B=Xk    -> Kd[b,h,s,d] bf16 (+bk)
// mode 2: A=Xv(s) B=Wv(f) -> Vtd[b,h,d,s] bf16 (+bv)
// mode 3/4: A=Wo(f) B=ctx(s) K-half z=mode-3 -> bf16 partial outp[z][s][f]
//   (R12: K-split z=2 -> 512 blocks = 2 blocks/CU. Partials summed in LN (f32).)
// R17 FAILED (BK=64 single-buffer): MfmaUtil 14%, VALUBusy 8.7% -- drain still exposed.
// R18: BK=32 with the R7 2-phase double-buffer (the structure that fixed attn): four 8KB
// LDS buffers (32KB, under the 34KB epilogue footprint -> same occupancy); stage tile t+1
// right after the barrier, compute tile t -> each barrier's vmcnt(0) drain lands after a
// full compute phase. 1 barrier per K-tile (32 vs 64). Bit-identical FLOP order.
__global__ __launch_bounds__(256, 3) void gemm_kernel(
    const u16* __restrict__ Xq, const u16* __restrict__ Xk, const u16* __restrict__ Xv,
    const u16* __restrict__ Wq, const u16* __restrict__ Wk, const u16* __restrict__ Wv,
    const u16* __restrict__ Wo, const u16* __restrict__ Ctx,
    const float* __restrict__ bq, const float* __restrict__ bk, const float* __restrict__ bv,
    u16* __restrict__ Qd, u16* __restrict__ Kd, u16* __restrict__ Vtd, u16* __restrict__ outp,
    int mode_base) {
  __shared__ __align__(16) u16 SH[17408];  // main loop: 4x4096 dbuf; epilogue: 34KB transpose tile
  u16* As0 = SH;
  u16* Bs0 = SH + 4096;
  u16* As1 = SH + 8192;
  u16* Bs1 = SH + 12288;
  const int mode = mode_base + blockIdx.z;
  const int tid = threadIdx.x;
  const int wid = tid >> 6, l = tid & 63, quad = l >> 4, ln = l & 15;
  const int wm = wid >> 1, wn = wid & 1;

  const u16 *A, *B; const float* bias;
  if (mode == 0)      { A = Wq; B = Xq;  bias = bq; }
  else if (mode == 1) { A = Wk; B = Xk;  bias = bk; }
  else if (mode == 2) { A = Xv; B = Wv;  bias = bv; }
  else                { A = Wo; B = Ctx; bias = bq; }
  int mBase, nBase;
  if (mode == 2) { mBase = blockIdx.x * 128; nBase = blockIdx.y * 128; }
  else           { mBase = blockIdx.y * 128; nBase = blockIdx.x * 128; }

  const int koff = (mode >= 3) ? (mode - 3) * 512 : 0;
  const int kLen = (mode >= 3) ? 512 : 1024;
  const u16* Ag = A + (size_t)mBase * 1024 + koff;
  const u16* Bg = B + (size_t)nBase * 1024 + koff;

  f32x4 acc[4][4] = {};

#define GSTAGE(AS, BS, t_)                                                      \
  do {                                                                          \
    const int k0_ = (t_) * 32;                                                  \
    int i0 = tid, i1 = tid + 256;                                               \
    gload_lds16(Ag + (size_t)(i0 & 127) * 1024 + k0_ + (i0 >> 7) * 8, &AS[i0 * 8]); \
    gload_lds16(Ag + (size_t)(i1 & 127) * 1024 + k0_ + (i1 >> 7) * 8, &AS[i1 * 8]); \
    gload_lds16(Bg + (size_t)(i0 & 127) * 1024 + k0_ + (i0 >> 7) * 8, &BS[i0 * 8]); \
    gload_lds16(Bg + (size_t)(i1 & 127) * 1024 + k0_ + (i1 >> 7) * 8, &BS[i1 * 8]); \
  } while (0)

#define GCOMP(AS, BS)                                                           \
  do {                                                                          \
    bf16x8 af[4], bf[4];                                                        \
    _Pragma("unroll")                                                           \
    for (int i = 0; i < 4; ++i)                                                 \
      af[i] = *(const bf16x8*)&AS[(quad * 128 + wm * 64 + i * 16 + ln) * 8];    \
    _Pragma("unroll")                                                           \
    for (int j = 0; j < 4; ++j)                                                 \
      bf[j] = *(const bf16x8*)&BS[(quad * 128 + wn * 64 + j * 16 + ln) * 8];    \
    _Pragma("unroll")                                                           \
    for (int i = 0; i < 4; ++i)                                                 \
      _Pragma("unroll")                                                         \
      for (int j = 0; j < 4; ++j)                                               \
        acc[i][j] = __builtin_amdgcn_mfma_f32_16x16x32_bf16(af[i], bf[j], acc[i][j], 0, 0, 0); \
  } while (0)

  const int nt2 = kLen >> 6;  // K-tile pairs: 16 (full K) or 8 (K-split)
  GSTAGE(As0, Bs0, 0);        // prologue: tile 0 -> buf0 (drain exposed once)
#pragma unroll 1
  for (int it2 = 0; it2 < nt2; ++it2) {
    __syncthreads();  // drains buf0 staging (issued one compute-phase ago); buf1 readers done
    GSTAGE(As1, Bs1, 2 * it2 + 1);
    GCOMP(As0, Bs0);
    __syncthreads();  // drains buf1 staging; buf0 readers done
    if (it2 < nt2 - 1) GSTAGE(As0, Bs0, 2 * it2 + 2);
    GCOMP(As1, Bs1);
  }
#undef GSTAGE
#undef GCOMP

  __syncthreads();  // all waves done with dbuf before reusing SH for the transpose

  if (mode <= 1) {
    const float bscale = (mode == 0) ? QSCALE : 1.0f;
#pragma unroll
    for (int i = 0; i < 4; ++i) {
      int f0 = wm * 64 + i * 16 + quad * 4;
      float4 bb = *(const float4*)(bias + mBase + f0);
#pragma unroll
      for (int j = 0; j < 4; ++j) {
        int sl = wn * 64 + j * 16 + ln;
        f32x4 v = acc[i][j];
        ushort4 o;
        o.x = f2bf(v[0] + bb.x * bscale); o.y = f2bf(v[1] + bb.y * bscale);
        o.z = f2bf(v[2] + bb.z * bscale); o.w = f2bf(v[3] + bb.w * bscale);
        *(ushort4*)&SH[sl * 136 + f0] = o;
      }
    }
    __syncthreads();
    u16* dstQK = (mode == 0) ? Qd : Kd;
#pragma unroll
    for (int p = 0; p < 8; ++p) {
      int sl = p * 16 + (tid >> 4);
      int fl = (tid & 15) * 8;
      uint4 w = *(const uint4*)&SH[sl * 136 + fl];
      int s = nBase + sl, f = mBase + fl;
      int h = f >> 6, d = f & 63, b = s >> 11, sr = s & 2047;
      *(uint4*)(dstQK + (((size_t)(b * 16 + h) * 2048 + sr) * 64 + d)) = w;
    }
  } else if (mode == 2) {
#pragma unroll
    for (int j = 0; j < 4; ++j) {
      int fl = wn * 64 + j * 16 + ln;
      float bb = bias[nBase + fl];
#pragma unroll
      for (int i = 0; i < 4; ++i) {
        int s0 = wm * 64 + i * 16 + quad * 4;
        f32x4 v = acc[i][j];
        ushort4 o;
        o.x = f2bf(v[0] + bb); o.y = f2bf(v[1] + bb);
        o.z = f2bf(v[2] + bb); o.w = f2bf(v[3] + bb);
        *(ushort4*)&SH[fl * 136 + s0] = o;
      }
    }
    __syncthreads();
#pragma unroll
    for (int p = 0; p < 8; ++p) {
      int fl = p * 16 + (tid >> 4);
      int sl = (tid & 15) * 8;
      uint4 w = *(const uint4*)&SH[fl * 136 + sl];
      int f = nBase + fl, s = mBase + sl;
      int h = f >> 6, d = f & 63, b = s >> 11, sr = s & 2047;
      *(uint4*)(Vtd + (((size_t)(b * 16 + h) * 64 + d) * 2048 + sr)) = w;
    }
  } else {
    // modes 3/4: bf16 partial, same SH-transpose as mode<=1, no bias, linear [s][f] dst
    u16* dst = outp + (size_t)(mode - 3) * (4096u * 1024u);
#pragma unroll
    for (int i = 0; i < 4; ++i) {
      int f0 = wm * 64 + i * 16 + quad * 4;
#pragma unroll
      for (int j = 0; j < 4; ++j) {
        int sl = wn * 64 + j * 16 + ln;
        f32x4 v = acc[i][j];
        ushort4 o;
        o.x = f2bf(v[0]); o.y = f2bf(v[1]);
        o.z = f2bf(v[2]); o.w = f2bf(v[3]);
        *(ushort4*)&SH[sl * 136 + f0] = o;
      }
    }
    __syncthreads();
#pragma unroll
    for (int p = 0; p < 8; ++p) {
      int sl = p * 16 + (tid >> 4);
      int fl = (tid & 15) * 8;
      uint4 w = *(const uint4*)&SH[sl * 136 + fl];
      *(uint4*)(dst + (size_t)(nBase + sl) * 1024 + mBase + fl) = w;
    }
  }
}

// ---------------- flash attention (no-max exp2 softmax), 128-q tiles, XCD-swizzled ----------------
// R16 (frozen): 512 blocks x 512 threads (8 waves, 16-q band each), QBLK=128 KVBLK=128,
// 2-phase dbuf staging via global_load_lds (R7), trunc-pack + setprio (R9), P stride-64
// XOR-swizzle. 2x80KiB LDS = 160KiB/CU, 16 waves/CU. >=2 blocks/CU is a hard constraint
// (R10/R12/R15: the per-tile vmcnt(0) drain needs a co-resident block to hide under).
__global__ __launch_bounds__(512, 4) void attn_kernel(
    const u16* __restrict__ Qg, const u16* __restrict__ Kg, const u16* __restrict__ Vtg,
    const unsigned* __restrict__ Mp, u16* __restrict__ ctx) {
  __shared__ __align__(16) u16 Ks0[8192];  // [dg 8][kv 128][8]
  __shared__ __align__(16) u16 Ks1[8192];
  __shared__ __align__(16) u16 Vs0[8192];  // [kvg 16][d 64][8]
  __shared__ __align__(16) u16 Vs1[8192];
  __shared__ __align__(16) u16 Ps[8192];   // [q 128][64] swizzled; reused as Os[128][64]
  const int tid = threadIdx.x;             // 0..511
  const int wid = tid >> 6, l = tid & 63, quad = l >> 4, ln = l & 15;
  const int q4 = quad * 4;
  const int L = blockIdx.x;
  const int bh = (L & 7) + 8 * (L >> 7);
  const int b = bh >> 4, h = bh & 15;
  const int qBase = ((L >> 3) & 15) * 128;
  const int wq = wid * 16;                 // wave's 16-q band (wid 0..7)
  const int sw = (ln & 7) << 3;            // P row XOR-swizzle, u16 units (row&7 == ln&7)

  bf16x8 qf[2];  // B-operand fragments of Q (col=q=ln row, k=d contiguous)
#pragma unroll
  for (int kc = 0; kc < 2; ++kc)
    qf[kc] = *(const bf16x8*)(Qg + (((size_t)bh * 2048 + qBase + wq + ln) * 64 +
                                    kc * 32 + quad * 8));

  f32x4 oacc[4] = {};
  f32x4 lsum = {};
  const bf16x8 vone = {(short)0x3F80, (short)0x3F80, (short)0x3F80, (short)0x3F80,
                       (short)0x3F80, (short)0x3F80, (short)0x3F80, (short)0x3F80};

  const unsigned* mrow = Mp + ((size_t)b * 2048 + qBase + wq + ln) * 64;  // 64 u32 / row

  const u16* KgB = Kg + (size_t)bh * 2048 * 64;
  const u16* VgB = Vtg + (size_t)bh * 64 * 2048;

#define STAGE_TILE(KS, VS, t_)                                                  \
  do {                                                                          \
    const int kvB_ = (t_) * 128;                                                \
    _Pragma("unroll")                                                           \
    for (int r_ = 0; r_ < 2; ++r_) {                                            \
      int c_ = r_ * 512 + tid;                                                  \
      gload_lds16(KgB + (size_t)(kvB_ + (c_ & 127)) * 64 + (c_ >> 7) * 8,       \
                  &KS[c_ * 8]);                                                 \
      gload_lds16(VgB + (size_t)(c_ & 63) * 2048 + kvB_ + (c_ >> 6) * 8,        \
                  &VS[c_ * 8]);                                                 \
    }                                                                           \
  } while (0)

#define COMPUTE_TILE(KS, VS, it_)                                                         \
  do {                                                                                    \
    unsigned ww[4];                                                                       \
    {                                                                                     \
      uint4 m0 = *(const uint4*)(mrow + (it_) * 4);                                       \
      ww[0] = m0.x; ww[1] = m0.y; ww[2] = m0.z; ww[3] = m0.w;                             \
    }                                                                                     \
    _Pragma("unroll")                                                                     \
    for (int hf = 0; hf < 2; ++hf) {                                                      \
      f32x4 s[4];                                                                         \
      __builtin_amdgcn_s_setprio(1);                                                      \
      _Pragma("unroll")                                                                   \
      for (int m2 = 0; m2 < 4; ++m2) {                                                    \
        int mt = hf * 4 + m2;                                                             \
        bf16x8 k0 = *(const bf16x8*)&KS[((0 + quad) * 128 + mt * 16 + ln) * 8];           \
        bf16x8 k1 = *(const bf16x8*)&KS[((4 + quad) * 128 + mt * 16 + ln) * 8];           \
        f32x4 z = {0.f, 0.f, 0.f, 0.f};                                                   \
        z = __builtin_amdgcn_mfma_f32_16x16x32_bf16(k0, qf[0], z, 0, 0, 0);               \
        s[m2] = __builtin_amdgcn_mfma_f32_16x16x32_bf16(k1, qf[1], z, 0, 0, 0);           \
      }                                                                                   \
      __builtin_amdgcn_s_setprio(0);                                                      \
      uint2 pk[4];                                                                        \
      _Pragma("unroll")                                                                   \
      for (int m2 = 0; m2 < 4; ++m2) {                                                    \
        int mt = hf * 4 + m2;                                                             \
        unsigned nib = (ww[mt >> 1] >> ((mt & 1) * 16 + q4)) & 0xFu;                      \
        float p0 = __builtin_amdgcn_exp2f((nib & 1u) ? s[m2][0] : -1e30f);                \
        float p1 = __builtin_amdgcn_exp2f((nib & 2u) ? s[m2][1] : -1e30f);                \
        float p2 = __builtin_amdgcn_exp2f((nib & 4u) ? s[m2][2] : -1e30f);                \
        float p3 = __builtin_amdgcn_exp2f((nib & 8u) ? s[m2][3] : -1e30f);                \
        pk[m2].x = __builtin_amdgcn_perm(__float_as_uint(p1), __float_as_uint(p0),        \
                                         0x07060302u);                                    \
        pk[m2].y = __builtin_amdgcn_perm(__float_as_uint(p3), __float_as_uint(p2),        \
                                         0x07060302u);                                    \
      }                                                                                   \
      /* P write -> PV read is intra-wave (own 16-row band): no barrier needed. */        \
      _Pragma("unroll")                                                                   \
      for (int m2 = 0; m2 < 4; ++m2)                                                      \
        *(uint2*)&Ps[(((wq + ln) * 64) + m2 * 16 + q4) ^ sw] = pk[m2];                    \
      __builtin_amdgcn_s_setprio(1);                                                      \
      _Pragma("unroll")                                                                   \
      for (int k2 = 0; k2 < 2; ++k2) {                                                    \
        int kc2 = hf * 2 + k2;                                                            \
        bf16x8 aP = *(const bf16x8*)&Ps[(((wq + ln) * 64) + k2 * 32 + quad * 8) ^ sw];    \
        _Pragma("unroll")                                                                 \
        for (int nt = 0; nt < 4; ++nt) {                                                  \
          bf16x8 bV = *(const bf16x8*)&VS[((kc2 * 4 + quad) * 64 + nt * 16 + ln) * 8];    \
          oacc[nt] = __builtin_amdgcn_mfma_f32_16x16x32_bf16(aP, bV, oacc[nt], 0, 0, 0);  \
        }                                                                                 \
        lsum = __builtin_amdgcn_mfma_f32_16x16x32_bf16(aP, vone, lsum, 0, 0, 0);          \
      }                                                                                   \
      __builtin_amdgcn_s_setprio(0);                                                      \
    }                                                                                     \
  } while (0)

  STAGE_TILE(Ks0, Vs0, 0);  // prologue: tile 0 -> buf0 (drain cost paid once)
#pragma unroll 1
  for (int it2 = 0; it2 < 8; ++it2) {
    __syncthreads();  // drains buf0 staging (issued one compute-phase ago); buf1 readers done
    STAGE_TILE(Ks1, Vs1, 2 * it2 + 1);
    COMPUTE_TILE(Ks0, Vs0, 2 * it2);
    __syncthreads();  // drains buf1 staging; buf0 readers done
    if (it2 < 7) STAGE_TILE(Ks0, Vs0, 2 * it2 + 2);
    COMPUTE_TILE(Ks1, Vs1, 2 * it2 + 1);
  }
#undef STAGE_TILE
#undef COMPUTE_TILE

  // epilogue: stage normalized O into Ps (own band only; P and Os bands coincide at stride 64)
  __syncthreads();  // all waves done with Ps as P
#pragma unroll
  for (int r = 0; r < 4; ++r) {
    float il = 1.0f / lsum[r];
    int q = wq + q4 + r;
#pragma unroll
    for (int nt = 0; nt < 4; ++nt)
      Ps[q * 64 + nt * 16 + ln] = f2bf(oacc[nt][r] * il);
  }
  __syncthreads();
#pragma unroll
  for (int r = 0; r < 2; ++r) {
    int c = r * 512 + tid;
    int q = c >> 3, ch = c & 7;
    *(uint4*)(ctx + ((size_t)(b * 2048 + qBase + q) * 1024 + h * 64 + ch * 8)) =
        *(const uint4*)&Ps[q * 64 + ch * 8];
  }
}

// ---------------- LayerNorm (fused partial-sum + bo + residual) over 1024 features ----------------
// R12: x is TWO bf16 K-half partials (8MB each); sum in f32 here.
__global__ __launch_bounds__(256) void ln_kernel(const u16* __restrict__ xp,
                                                 const float* __restrict__ resid,
                                                 const float* __restrict__ bo,
                                                 const float* __restrict__ gamma,
                                                 const float* __restrict__ beta,
                                                 float* __restrict__ out) {
  __shared__ float red[8];
  const int tid = threadIdx.x;
  const size_t row = blockIdx.x;
  ushort4 pa = ((const ushort4*)(xp + row * 1024))[tid];
  ushort4 pb = ((const ushort4*)(xp + 4096u * 1024u + row * 1024))[tid];
  const float4 rr = ((const float4*)(resid + row * 1024))[tid];
  const float4 bb = ((const float4*)bo)[tid];
  float4 v;
  v.x = bf2f(pa.x) + bf2f(pb.x) + rr.x + bb.x;
  v.y = bf2f(pa.y) + bf2f(pb.y) + rr.y + bb.y;
  v.z = bf2f(pa.z) + bf2f(pb.z) + rr.z + bb.z;
  v.w = bf2f(pa.w) + bf2f(pb.w) + rr.w + bb.w;
  float s1 = v.x + v.y + v.z + v.w;
  float s2 = v.x * v.x + v.y * v.y + v.z * v.z + v.w * v.w;
#pragma unroll
  for (int o = 32; o >= 1; o >>= 1) {
    s1 += __shfl_xor(s1, o);
    s2 += __shfl_xor(s2, o);
  }
  if ((tid & 63) == 0) { red[(tid >> 6) * 2] = s1; red[(tid >> 6) * 2 + 1] = s2; }
  __syncthreads();
  s1 = red[0] + red[2] + red[4] + red[6];
  s2 = red[1] + red[3] + red[5] + red[7];
  float mu = s1 * (1.f / 1024.f);
  float var = s2 * (1.f / 1024.f) - mu * mu;
  float inv = rsqrtf(var + 1e-5f);
  float4 g = ((const float4*)gamma)[tid];
  float4 be = ((const float4*)beta)[tid];
  float4 o;
  o.x = (v.x - mu) * inv * g.x + be.x;
  o.y = (v.y - mu) * inv * g.y + be.y;
  o.z = (v.z - mu) * inv * g.z + be.z;
  o.w = (v.w - mu) * inv * g.w + be.w;
  ((float4*)(out + row * 1024))[tid] = o;
}

extern "C" void kernel_launch(void* const* d_in, const int* in_sizes, int n_in,
                              void* d_out, int out_size, void* d_ws, size_t ws_size,
                              hipStream_t stream) {
  const float* query = (const float*)d_in[0];
  const float* key   = (const float*)d_in[1];
  const float* value = (const float*)d_in[2];
  const int*   mask  = (const int*)d_in[3];
  const float* w_q = (const float*)d_in[4];
  const float* b_q = (const float*)d_in[5];
  const float* w_k = (const float*)d_in[6];
  const float* b_k = (const float*)d_in[7];
  const float* w_v = (const float*)d_in[8];
  const float* b_v = (const float*)d_in[9];
  const float* w_o = (const float*)d_in[10];
  const float* b_o = (const float*)d_in[11];
  const float* ln_g = (const float*)d_in[12];
  const float* ln_b = (const float*)d_in[13];
  float* out = (float*)d_out;

  char* ws = (char*)d_ws;
  u16* Xq = (u16*)(ws + ((size_t)0 << 20));   // 8MB, reused as ctx after QKV GEMM
  u16* Xk = (u16*)(ws + ((size_t)8 << 20));   // 8MB  } reused as outpre (2x8MB bf16 partials)
  u16* Xv = (u16*)(ws + ((size_t)16 << 20));  // 8MB  }
  u16* outpre = (u16*)(ws + ((size_t)8 << 20));
  u16* Wq = (u16*)(ws + ((size_t)24 << 20));
  u16* Wk = (u16*)(ws + ((size_t)26 << 20));
  u16* Wv = (u16*)(ws + ((size_t)28 << 20));
  u16* Wo = (u16*)(ws + ((size_t)30 << 20));
  u16* Qd = (u16*)(ws + ((size_t)32 << 20));   // [b,h,s,64] bf16
  u16* Kd = (u16*)(ws + ((size_t)40 << 20));   // [b,h,s,64]
  u16* Vtd = (u16*)(ws + ((size_t)48 << 20));  // [b,h,64,s]
  unsigned long long* Mp = (unsigned long long*)(ws + ((size_t)56 << 20));  // 1MB
  u16* ctx = Xq;

  prep_kernel<<<20480, 256, 0, stream>>>(query, key, value, w_q, w_k, w_v, w_o, mask,
                                         Xq, Xk, Xv, Wq, Wk, Wv, Wo, Mp);
  gemm_kernel<<<dim3(32, 8, 3), 256, 0, stream>>>(Xq, Xk, Xv, Wq, Wk, Wv, Wo, ctx,
      b_q, b_k, b_v, Qd, Kd, Vtd, outpre, 0);
  attn_kernel<<<dim3(512), 512, 0, stream>>>(Qd, Kd, Vtd, (const unsigned*)Mp, ctx);
  gemm_kernel<<<dim3(32, 8, 2), 256, 0, stream>>>(Xq, Xk, Xv, Wq, Wk, Wv, Wo, ctx,
      b_q, b_k, b_v, Qd, Kd, Vtd, outpre, 3);
  ln_kernel<<<4096, 256, 0, stream>>>(outpre, query, b_o, ln_g, ln_b, out);
}